// Round 5
// baseline (301.683 us; speedup 1.0000x reference)
//
#include <hip/hip_runtime.h>
#include <stdint.h>

typedef __attribute__((ext_vector_type(8))) __bf16 bf16x8;
typedef __attribute__((ext_vector_type(4))) __bf16 bf16x4;
typedef __attribute__((ext_vector_type(4))) float f32x4;
typedef __attribute__((ext_vector_type(4))) float fl4;
typedef __attribute__((ext_vector_type(8))) unsigned short us8;
typedef __attribute__((ext_vector_type(4))) unsigned short us4;

__device__ __forceinline__ unsigned short f2bf(float f) {
  union { float f; unsigned int u; } v;
  v.f = f;
  unsigned int r = v.u + 0x7FFFu + ((v.u >> 16) & 1u);
  return (unsigned short)(r >> 16);
}

#define GLOAD_LDS16(g, l)                                                   \
  __builtin_amdgcn_global_load_lds(                                         \
      (const __attribute__((address_space(1))) void*)(g),                   \
      (__attribute__((address_space(3))) void*)(l), 16, 0, 0)

// ---------------- fp32 -> bf16 conversion (weights only) ----------------
__global__ void f32_to_bf16_kernel(const float* __restrict__ in,
                                   unsigned short* __restrict__ out, int n) {
  int i = (blockIdx.x * blockDim.x + threadIdx.x) * 4;
  if (i + 3 < n) {
    fl4 v = *(const fl4*)(in + i);
    us4 o;
    o[0] = f2bf(v[0]);
    o[1] = f2bf(v[1]);
    o[2] = f2bf(v[2]);
    o[3] = f2bf(v[3]);
    *(us4*)(out + i) = o;
  }
}

// ------- 128x128 4-wave double-buffered 2-phase GEMM, f32 A fused-convert --
// C = A(MxK,f32) * B(NxK,bf16)^T + bias -> bf16.  A converted to bf16 in-reg
// during staging (reg path: global f32 -> cvt -> swizzled ds_write_b128);
// B staged via global_load_lds with pre-swizzled source (T2).
// One __syncthreads per K-tile (drains vmcnt+lgkmcnt; race-free per R4).
__global__ __launch_bounds__(256, 2) void gemm128f_kernel(
    const float* __restrict__ Af, const unsigned short* __restrict__ B,
    const float* __restrict__ bias, unsigned short* __restrict__ Cout, int M,
    int N, int K, int NT) {
  __shared__ __align__(16) unsigned short lds[32768];  // 64 KB
  char* base = (char*)lds;

  const int tid = threadIdx.x;
  const int lane = tid & 63;
  const int wid = tid >> 6;
  const int lr = lane & 15;
  const int lg = lane >> 4;
  const int wr = (wid >> 1) * 64;
  const int wc = (wid & 1) * 64;

  // supertile-32 mapping
  const int bid = blockIdx.x;
  const int bm = ((bid & 31) + (bid / (32 * NT)) * 32) << 7;
  const int bn = (((bid >> 5) % NT)) << 7;

  const int srow = tid >> 3;  // 0..31
  const int scolsw = ((tid & 7) << 4) ^ ((srow & 7) << 4);
  const int awch = ((tid & 7) << 4) ^ ((srow & 7) << 4);
  const char* Bg = (const char*)B;
  const size_t Kb = (size_t)K * 2;

  fl4 fa[4][2];

#define STAGE_B(kt, p)                                                         \
  {                                                                            \
    char* lb_ = base + (p)*32768 + 16384;                                      \
    _Pragma("unroll") for (int i_ = 0; i_ < 4; ++i_) {                         \
      GLOAD_LDS16(Bg + (size_t)(bn + srow + i_ * 32) * Kb + (kt)*128 + scolsw, \
                  lb_ + srow * 128 + i_ * 4096 + (tid & 7) * 16);              \
    }                                                                          \
  }
#define LOAD_A(kt)                                                             \
  _Pragma("unroll") for (int i_ = 0; i_ < 4; ++i_) {                           \
    const float* ap_ =                                                         \
        Af + (size_t)(bm + srow + i_ * 32) * K + (kt)*64 + (tid & 7) * 8;      \
    fa[i_][0] = *(const fl4*)(ap_);                                            \
    fa[i_][1] = *(const fl4*)(ap_ + 4);                                        \
  }
#define WRITE_A(p)                                                             \
  {                                                                            \
    char* la_ = base + (p)*32768;                                              \
    _Pragma("unroll") for (int i_ = 0; i_ < 4; ++i_) {                         \
      bf16x8 w_;                                                               \
      _Pragma("unroll") for (int e_ = 0; e_ < 4; ++e_) {                       \
        w_[e_] = (__bf16)fa[i_][0][e_];                                        \
        w_[e_ + 4] = (__bf16)fa[i_][1][e_];                                    \
      }                                                                        \
      *(bf16x8*)(la_ + (srow + i_ * 32) * 128 + awch) = w_;                    \
    }                                                                          \
  }

  const int swz = (lr & 7) << 4;
  const int ck0 = (lg << 4) ^ swz;
  const int ck1 = (64 + (lg << 4)) ^ swz;

  f32x4 acc[4][4];
#pragma unroll
  for (int m = 0; m < 4; ++m)
#pragma unroll
    for (int n = 0; n < 4; ++n) acc[m][n] = (f32x4){0.f, 0.f, 0.f, 0.f};

  const int nkt = K >> 6;

  STAGE_B(0, 0);
  LOAD_A(0);
  WRITE_A(0);
  __syncthreads();

  for (int kt = 0; kt < nkt; ++kt) {
    const int p = kt & 1;
    if (kt + 1 < nkt) {
      STAGE_B(kt + 1, p ^ 1);
      LOAD_A(kt + 1);
    }
    const char* la = base + p * 32768;
    const char* lb = la + 16384;
    bf16x8 af[4][2], bfr[4][2];
#pragma unroll
    for (int m = 0; m < 4; ++m) {
      const int arow = (wr + m * 16 + lr) << 7;
      af[m][0] = *(const bf16x8*)(la + arow + ck0);
      af[m][1] = *(const bf16x8*)(la + arow + ck1);
    }
#pragma unroll
    for (int n = 0; n < 4; ++n) {
      const int brow = (wc + n * 16 + lr) << 7;
      bfr[n][0] = *(const bf16x8*)(lb + brow + ck0);
      bfr[n][1] = *(const bf16x8*)(lb + brow + ck1);
    }
#pragma unroll
    for (int kk = 0; kk < 2; ++kk)
#pragma unroll
      for (int m = 0; m < 4; ++m)
#pragma unroll
        for (int n = 0; n < 4; ++n)
          acc[m][n] = __builtin_amdgcn_mfma_f32_16x16x32_bf16(
              af[m][kk], bfr[n][kk], acc[m][n], 0, 0, 0);
    if (kt + 1 < nkt) WRITE_A(p ^ 1);  // waits its loads; disjoint from reads
    __syncthreads();
  }
#undef STAGE_B
#undef LOAD_A
#undef WRITE_A

  const int crow0 = bm + wr + lg * 4;
  const int ccol0 = bn + wc + lr;
#pragma unroll
  for (int n = 0; n < 4; ++n) {
    const int col = ccol0 + n * 16;
    const float bv = bias[col];
#pragma unroll
    for (int m = 0; m < 4; ++m) {
#pragma unroll
      for (int j = 0; j < 4; ++j) {
        const int row = crow0 + m * 16 + j;
        Cout[(size_t)row * N + col] = f2bf(acc[m][n][j] + bv);
      }
    }
  }
}

// -------- fused attention + proj: one block (8 waves) per window b ---------
// Phase 1 (attn): 2 head-groups of 4 waves; per head: R4's verified structure
// (stage q/k/vT -> S=QK^T + scale+bias+mask -> in-reg softmax -> P lds ->
// PV) but attn-out goes to LDS AO[64][520] instead of global.
// Phase 2 (proj): out(64x512,f32) = AO(64x512) @ proj_w^T + proj_b; K=512 in
// 16 chunks of 32; proj_w chunk staged [512][44] (b64-aligned, conflict-free)
// with register prefetch double-buffering.
__global__ __launch_bounds__(512, 1) void attnproj_kernel(
    const unsigned short* __restrict__ qkv, const float* __restrict__ abias,
    const float* __restrict__ mask, const unsigned short* __restrict__ wp,
    const float* __restrict__ pbias, float* __restrict__ out) {
  __shared__ __align__(16) unsigned short SH[33280 + 24576];  // 113 KB
  unsigned short* AO = SH;  // [64][520]

  const int tid = threadIdx.x;
  const int g = tid >> 8;           // head-group 0/1
  const int gtid = tid & 255;
  const int gwid = (tid >> 6) & 3;  // wave within group
  const int lane = tid & 63;
  const int lr = lane & 15;
  const int lg = lane >> 4;
  const int lk8 = lg * 8;
  const int b = blockIdx.x;

  unsigned short* gb = SH + 33280 + g * 12032;
  unsigned short* lq = gb;          // [64][40]
  unsigned short* lk = gb + 2560;   // [64][40]
  unsigned short* lvT = gb + 5120;  // [32][72]
  unsigned short* lp = gb + 7424;   // [64][72]

  const float scale = 0.17677669529663687f;  // 32^-0.5
  const int row0 = gwid * 16 + lg * 4;

  for (int hr = 0; hr < 8; ++hr) {
    const int h = hr * 2 + g;
    // ---- stage q, k, vT for this head
    {
      const int r = gtid >> 2;
      const int d0 = (gtid & 3) * 8;
      const size_t bse = (size_t)(b * 64 + r) * 1536 + h * 32 + d0;
      us8 qv = *(const us8*)(qkv + bse);
      us8 kv = *(const us8*)(qkv + bse + 512);
      us8 vv = *(const us8*)(qkv + bse + 1024);
      *(us8*)(lq + r * 40 + d0) = qv;
      *(us8*)(lk + r * 40 + d0) = kv;
#pragma unroll
      for (int i = 0; i < 8; ++i) lvT[(d0 + i) * 72 + r] = vv[i];
    }
    __syncthreads();

    // ---- S = q @ k^T, fused scale + bias + mask
    f32x4 s[4];
    {
      bf16x8 aq = *(const bf16x8*)(lq + (gwid * 16 + lr) * 40 + lk8);
#pragma unroll
      for (int n = 0; n < 4; ++n) {
        bf16x8 bk = *(const bf16x8*)(lk + (n * 16 + lr) * 40 + lk8);
        f32x4 z = {0.f, 0.f, 0.f, 0.f};
        s[n] = __builtin_amdgcn_mfma_f32_16x16x32_bf16(aq, bk, z, 0, 0, 0);
      }
    }
#pragma unroll
    for (int j = 0; j < 4; ++j) {
      const int row = row0 + j;
      const float* ab = abias + (h * 64 + row) * 64 + lr;
      const float* mk = mask + ((size_t)b * 64 + row) * 64 + lr;
#pragma unroll
      for (int n = 0; n < 4; ++n)
        s[n][j] = s[n][j] * scale + ab[n * 16] + mk[n * 16];
    }

    // ---- in-register softmax (reduce over n in-reg, lr via shfl 16-group)
    float mx[4], sm[4];
#pragma unroll
    for (int j = 0; j < 4; ++j)
      mx[j] = fmaxf(fmaxf(s[0][j], s[1][j]), fmaxf(s[2][j], s[3][j]));
#pragma unroll
    for (int xm = 1; xm <= 8; xm <<= 1)
#pragma unroll
      for (int j = 0; j < 4; ++j) mx[j] = fmaxf(mx[j], __shfl_xor(mx[j], xm));
#pragma unroll
    for (int j = 0; j < 4; ++j) sm[j] = 0.f;
#pragma unroll
    for (int n = 0; n < 4; ++n)
#pragma unroll
      for (int j = 0; j < 4; ++j) {
        const float e = __expf(s[n][j] - mx[j]);
        s[n][j] = e;
        sm[j] += e;
      }
#pragma unroll
    for (int xm = 1; xm <= 8; xm <<= 1)
#pragma unroll
      for (int j = 0; j < 4; ++j) sm[j] += __shfl_xor(sm[j], xm);
#pragma unroll
    for (int j = 0; j < 4; ++j) sm[j] = 1.f / sm[j];
#pragma unroll
    for (int n = 0; n < 4; ++n)
#pragma unroll
      for (int j = 0; j < 4; ++j)
        lp[(row0 + j) * 72 + n * 16 + lr] = f2bf(s[n][j] * sm[j]);
    __syncthreads();

    // ---- O = P @ V -> AO LDS
    f32x4 o[2];
    o[0] = (f32x4){0.f, 0.f, 0.f, 0.f};
    o[1] = o[0];
#pragma unroll
    for (int kk = 0; kk < 2; ++kk) {
      bf16x8 pa = *(const bf16x8*)(lp + (gwid * 16 + lr) * 72 + kk * 32 + lk8);
#pragma unroll
      for (int d = 0; d < 2; ++d) {
        bf16x8 vb = *(const bf16x8*)(lvT + (d * 16 + lr) * 72 + kk * 32 + lk8);
        o[d] = __builtin_amdgcn_mfma_f32_16x16x32_bf16(pa, vb, o[d], 0, 0, 0);
      }
    }
#pragma unroll
    for (int d = 0; d < 2; ++d) {
      const int col = h * 32 + d * 16 + lr;
#pragma unroll
      for (int j = 0; j < 4; ++j) AO[(row0 + j) * 520 + col] = f2bf(o[d][j]);
    }
    __syncthreads();  // protect group bufs + AO before next round / proj
  }

  // ================= proj phase =================
  unsigned short* lwp = SH + 33280;  // [512][44] aliases group bufs
  const int wv = tid >> 6;           // wave 0..7 -> out cols wv*64..+63
  const int prow = tid >> 2;         // 0..127 (+ s*128)
  const int pc = (tid & 3) * 8;      // elem chunk within 32-wide k-slice

  f32x4 pacc[4][4];
#pragma unroll
  for (int m = 0; m < 4; ++m)
#pragma unroll
    for (int n = 0; n < 4; ++n) pacc[m][n] = (f32x4){0.f, 0.f, 0.f, 0.f};

  us8 wreg[4];
#pragma unroll
  for (int s0 = 0; s0 < 4; ++s0)
    wreg[s0] = *(const us8*)(wp + (size_t)(prow + s0 * 128) * 512 + pc);
#pragma unroll
  for (int s0 = 0; s0 < 4; ++s0) {
    const int ro = (prow + s0 * 128) * 44 + pc;
    *(us4*)(lwp + ro) = (us4){wreg[s0][0], wreg[s0][1], wreg[s0][2], wreg[s0][3]};
    *(us4*)(lwp + ro + 4) = (us4){wreg[s0][4], wreg[s0][5], wreg[s0][6], wreg[s0][7]};
  }
  __syncthreads();

  for (int kt = 0; kt < 16; ++kt) {
    if (kt < 15) {
#pragma unroll
      for (int s0 = 0; s0 < 4; ++s0)
        wreg[s0] = *(const us8*)(wp + (size_t)(prow + s0 * 128) * 512 +
                                 (kt + 1) * 32 + pc);
    }
    bf16x8 af[4], bfr[4];
#pragma unroll
    for (int mq = 0; mq < 4; ++mq)
      af[mq] = *(const bf16x8*)(AO + (mq * 16 + lr) * 520 + kt * 32 + lk8);
#pragma unroll
    for (int n = 0; n < 4; ++n) {
      const int ro = (wv * 64 + n * 16 + lr) * 44 + lk8;
      union { bf16x8 v8; bf16x4 v4[2]; } u;
      u.v4[0] = *(const bf16x4*)(lwp + ro);
      u.v4[1] = *(const bf16x4*)(lwp + ro + 4);
      bfr[n] = u.v8;
    }
#pragma unroll
    for (int mq = 0; mq < 4; ++mq)
#pragma unroll
      for (int n = 0; n < 4; ++n)
        pacc[mq][n] = __builtin_amdgcn_mfma_f32_16x16x32_bf16(
            af[mq], bfr[n], pacc[mq][n], 0, 0, 0);
    __syncthreads();  // all reads of lwp(kt) done
    if (kt < 15) {
#pragma unroll
      for (int s0 = 0; s0 < 4; ++s0) {
        const int ro = (prow + s0 * 128) * 44 + pc;
        *(us4*)(lwp + ro) =
            (us4){wreg[s0][0], wreg[s0][1], wreg[s0][2], wreg[s0][3]};
        *(us4*)(lwp + ro + 4) =
            (us4){wreg[s0][4], wreg[s0][5], wreg[s0][6], wreg[s0][7]};
      }
      __syncthreads();  // chunk kt+1 visible
    }
  }

  // ---- epilogue: + proj_b, write f32
#pragma unroll
  for (int n = 0; n < 4; ++n) {
    const int col = wv * 64 + n * 16 + lr;
    const float bv = pbias[col];
#pragma unroll
    for (int mq = 0; mq < 4; ++mq) {
#pragma unroll
      for (int j = 0; j < 4; ++j) {
        const int row = mq * 16 + lg * 4 + j;
        out[(size_t)(b * 64 + row) * 512 + col] = pacc[mq][n][j] + bv;
      }
    }
  }
}

// ---------------- launch ----------------
extern "C" void kernel_launch(void* const* d_in, const int* in_sizes, int n_in,
                              void* d_out, int out_size, void* d_ws,
                              size_t ws_size, hipStream_t stream) {
  (void)in_sizes; (void)n_in; (void)out_size; (void)ws_size;
  const float* x = (const float*)d_in[0];
  const float* abias = (const float*)d_in[1];
  const float* mask = (const float*)d_in[2];
  const float* qkv_w = (const float*)d_in[3];
  const float* qkv_b = (const float*)d_in[4];
  const float* proj_w = (const float*)d_in[5];
  const float* proj_b = (const float*)d_in[6];

  char* ws = (char*)d_ws;
  unsigned short* ws_qkv = (unsigned short*)(ws);              // 100.7 MB
  unsigned short* ws_wq = (unsigned short*)(ws + 100663296);   // 1.5 MB
  unsigned short* ws_wp = (unsigned short*)(ws + 102236160);   // 0.5 MB

  f32_to_bf16_kernel<<<768, 256, 0, stream>>>(qkv_w, ws_wq, 786432);
  f32_to_bf16_kernel<<<256, 256, 0, stream>>>(proj_w, ws_wp, 262144);

  // qkv: M=32768, N=1536 (NT=12), K=512; A = x (f32, converted in-kernel)
  gemm128f_kernel<<<3072, 256, 0, stream>>>(x, ws_wq, qkv_b, ws_qkv, 32768,
                                            1536, 512, 12);

  // fused attention + proj: one block per window
  attnproj_kernel<<<512, 512, 0, stream>>>(ws_qkv, abias, mask, ws_wp, proj_b,
                                           (float*)d_out);
}

// Round 6
// 259.946 us; speedup vs baseline: 1.1606x; 1.1606x over previous
//
#include <hip/hip_runtime.h>
#include <stdint.h>

typedef __attribute__((ext_vector_type(8))) __bf16 bf16x8;
typedef __attribute__((ext_vector_type(4))) float f32x4;
typedef __attribute__((ext_vector_type(4))) float fl4;
typedef __attribute__((ext_vector_type(8))) unsigned short us8;
typedef __attribute__((ext_vector_type(4))) unsigned short us4;

__device__ __forceinline__ unsigned short f2bf(float f) {
  union { float f; unsigned int u; } v;
  v.f = f;
  unsigned int r = v.u + 0x7FFFu + ((v.u >> 16) & 1u);
  return (unsigned short)(r >> 16);
}

#define GLOAD_LDS16(g, l)                                                   \
  __builtin_amdgcn_global_load_lds(                                         \
      (const __attribute__((address_space(1))) void*)(g),                   \
      (__attribute__((address_space(3))) void*)(l), 16, 0, 0)

// ------------- fused fp32 -> bf16 conversion (x, qkv_w, proj_w) -----------
__global__ void convert_all_kernel(const float* __restrict__ x,
                                   const float* __restrict__ wq,
                                   const float* __restrict__ wp,
                                   unsigned short* __restrict__ ox,
                                   unsigned short* __restrict__ owq,
                                   unsigned short* __restrict__ owp) {
  const int i = (blockIdx.x * blockDim.x + threadIdx.x) * 4;
  const float* src;
  unsigned short* dst;
  int off;
  if (i < 16777216) {
    src = x; dst = ox; off = i;
  } else if (i < 17563648) {
    src = wq; dst = owq; off = i - 16777216;
  } else {
    src = wp; dst = owp; off = i - 17563648;
  }
  fl4 v = *(const fl4*)(src + off);
  us4 o;
  o[0] = f2bf(v[0]);
  o[1] = f2bf(v[1]);
  o[2] = f2bf(v[2]);
  o[3] = f2bf(v[3]);
  *(us4*)(dst + off) = o;
}

// ------- 128x128 8-wave double-buffered 2-phase bf16 NT GEMM ----
// C = A(MxK) * B(NxK)^T + bias. A,B row-major K-contiguous bf16.
// BM=BN=128, BK=64, 512 threads (8 waves: 2M x 4N), per-wave C = 64x32
// (4x2 frags of 16x16), mfma_f32_16x16x32_bf16.
// LDS 64 KB: [2 buf][A 16KB + B 16KB], T2 swizzle byte ^= ((row&7)<<4)
// via inverse-swizzled global source (linear global_load_lds dest) +
// swizzled ds_read. Prefetch STAGE(kt+1) issued before compute of kt;
// ONE __syncthreads() per K-tile (drains vmcnt AND lgkmcnt: prefetched tile
// landed + all LDS reads of the overwrite-target buffer complete — the raw
// s_barrier w/o lgkmcnt drain raced under graph replay in R3).
// 8 waves (vs R4's 4) doubles resident waves/CU at identical LDS ->
// 2 blocks/CU x 8 = 16 waves/CU to hide the 2-phase stage+drain stall.
template <bool OUT_BF16>
__global__ __launch_bounds__(512, 4) void gemm128_kernel(
    const unsigned short* __restrict__ A, const unsigned short* __restrict__ B,
    const float* __restrict__ bias, void* __restrict__ Cout, int M, int N,
    int K, int NT) {
  __shared__ __align__(16) unsigned short lds[32768];  // 64 KB
  char* base = (char*)lds;

  const int tid = threadIdx.x;
  const int lane = tid & 63;
  const int wid = tid >> 6;
  const int lr = lane & 15;
  const int lg = lane >> 4;
  const int wm = wid >> 2;  // 0..1  (64-row slab)
  const int wn = wid & 3;   // 0..3  (32-col slab)

  // supertile-32 mapping: 32 consecutive M-tiles x all NT N-tiles per super-row
  const int bid = blockIdx.x;
  const int bm = ((bid & 31) + (bid / (32 * NT)) * 32) << 7;
  const int bn = (((bid >> 5) % NT)) << 7;

  // staging: thread t covers rows srow, srow+64; 16B col chunk (t&7)*16,
  // source col pre-swizzled so LDS[row][c'] = data[row][c' ^ ((row&7)<<4)]
  // (row+64 has same (row&7) -> same swizzle).
  const int srow = tid >> 3;  // 0..63
  const int scsw = ((tid & 7) << 4) ^ ((srow & 7) << 4);
  const char* Ag = (const char*)A;
  const char* Bg = (const char*)B;
  const size_t Kb = (size_t)K * 2;

#define STAGE(kt, p)                                                           \
  {                                                                            \
    char* la_ = base + (p)*32768;                                              \
    char* lb_ = la_ + 16384;                                                   \
    _Pragma("unroll") for (int i_ = 0; i_ < 2; ++i_) {                         \
      GLOAD_LDS16(Ag + (size_t)(bm + srow + i_ * 64) * Kb + (kt)*128 + scsw,   \
                  la_ + (srow + i_ * 64) * 128 + (tid & 7) * 16);              \
      GLOAD_LDS16(Bg + (size_t)(bn + srow + i_ * 64) * Kb + (kt)*128 + scsw,   \
                  lb_ + (srow + i_ * 64) * 128 + (tid & 7) * 16);              \
    }                                                                          \
  }

  // swizzled ds_read col offsets
  const int swz = (lr & 7) << 4;
  const int ck0 = (lg << 4) ^ swz;         // kk=0
  const int ck1 = (64 + (lg << 4)) ^ swz;  // kk=1

  f32x4 acc[4][2];
#pragma unroll
  for (int m = 0; m < 4; ++m)
#pragma unroll
    for (int n = 0; n < 2; ++n) acc[m][n] = (f32x4){0.f, 0.f, 0.f, 0.f};

  const int nkt = K >> 6;

  STAGE(0, 0);
  __syncthreads();  // tile 0 landed (vmcnt drained)

  for (int kt = 0; kt < nkt; ++kt) {
    const int p = kt & 1;
    if (kt + 1 < nkt) STAGE(kt + 1, p ^ 1);  // prefetch overlaps compute

    const char* la = base + p * 32768;
    const char* lb = la + 16384;
    bf16x8 af[4][2], bfr[2][2];
#pragma unroll
    for (int m = 0; m < 4; ++m) {
      const int arow = (wm * 64 + m * 16 + lr) << 7;
      af[m][0] = *(const bf16x8*)(la + arow + ck0);
      af[m][1] = *(const bf16x8*)(la + arow + ck1);
    }
#pragma unroll
    for (int n = 0; n < 2; ++n) {
      const int brow = (wn * 32 + n * 16 + lr) << 7;
      bfr[n][0] = *(const bf16x8*)(lb + brow + ck0);
      bfr[n][1] = *(const bf16x8*)(lb + brow + ck1);
    }
#pragma unroll
    for (int kk = 0; kk < 2; ++kk)
#pragma unroll
      for (int m = 0; m < 4; ++m)
#pragma unroll
        for (int n = 0; n < 2; ++n)
          acc[m][n] = __builtin_amdgcn_mfma_f32_16x16x32_bf16(
              af[m][kk], bfr[n][kk], acc[m][n], 0, 0, 0);
    // drains vmcnt (next tile landed) AND lgkmcnt (this tile's ds_reads
    // complete -> safe for anyone to overwrite buffer p next iteration)
    __syncthreads();
  }
#undef STAGE

  // epilogue: C/D layout col = lane&15, row = lg*4 + j
  const int crow0 = bm + wm * 64 + lg * 4;
  const int ccol0 = bn + wn * 32 + lr;
#pragma unroll
  for (int n = 0; n < 2; ++n) {
    const int col = ccol0 + n * 16;
    const float bv = bias[col];
#pragma unroll
    for (int m = 0; m < 4; ++m) {
#pragma unroll
      for (int j = 0; j < 4; ++j) {
        const int row = crow0 + m * 16 + j;
        const float val = acc[m][n][j] + bv;
        if (OUT_BF16)
          ((unsigned short*)Cout)[(size_t)row * N + col] = f2bf(val);
        else
          ((float*)Cout)[(size_t)row * N + col] = val;
      }
    }
  }
}

// ---------------- attention: one WG (4 waves) per (b, h) ----------------
// In-register softmax on S fragments; XCD-chunked block remap.
__global__ __launch_bounds__(256, 4) void attn_kernel(
    const unsigned short* __restrict__ qkv, const float* __restrict__ abias,
    const float* __restrict__ mask, unsigned short* __restrict__ out) {
  __shared__ __align__(16) unsigned short lq[64 * 40];
  __shared__ __align__(16) unsigned short lk[64 * 40];
  __shared__ __align__(16) unsigned short lvT[32 * 72];
  __shared__ __align__(16) unsigned short lp[64 * 72];

  // XCD-chunked: all 16 heads of a window on the same XCD (shared qkv lines)
  const int bid = blockIdx.x;
  const int id2 = (bid & 7) * 1024 + (bid >> 3);
  const int b = id2 >> 4;
  const int h = id2 & 15;
  const int tid = threadIdx.x;
  const int lane = tid & 63;
  const int wid = tid >> 6;
  const int lr = lane & 15;
  const int lg = lane >> 4;
  const int lk8 = lg * 8;

  {
    const int r = tid >> 2;
    const int d0 = (tid & 3) * 8;
    const size_t bse = (size_t)(b * 64 + r) * 1536 + h * 32 + d0;
    us8 qv = *(const us8*)(qkv + bse);
    us8 kv = *(const us8*)(qkv + bse + 512);
    us8 vv = *(const us8*)(qkv + bse + 1024);
    *(us8*)(lq + r * 40 + d0) = qv;
    *(us8*)(lk + r * 40 + d0) = kv;
#pragma unroll
    for (int i = 0; i < 8; ++i) lvT[(d0 + i) * 72 + r] = vv[i];
  }
  __syncthreads();

  // S = q @ k^T (wave owns rows wid*16..+15), fused scale+bias+mask in-frag
  f32x4 s[4];
  {
    bf16x8 aq = *(const bf16x8*)(lq + (wid * 16 + lr) * 40 + lk8);
#pragma unroll
    for (int n = 0; n < 4; ++n) {
      bf16x8 bk = *(const bf16x8*)(lk + (n * 16 + lr) * 40 + lk8);
      f32x4 z = {0.f, 0.f, 0.f, 0.f};
      s[n] = __builtin_amdgcn_mfma_f32_16x16x32_bf16(aq, bk, z, 0, 0, 0);
    }
  }
  const float scale = 0.17677669529663687f;
  const int row0 = wid * 16 + lg * 4;  // + j
#pragma unroll
  for (int j = 0; j < 4; ++j) {
    const int row = row0 + j;
    const float* ab = abias + (h * 64 + row) * 64 + lr;
    const float* mk = mask + ((size_t)b * 64 + row) * 64 + lr;
#pragma unroll
    for (int n = 0; n < 4; ++n)
      s[n][j] = s[n][j] * scale + ab[n * 16] + mk[n * 16];
  }

  // in-register softmax per row j: reduce over n (in-reg) and lr (shfl 16-group)
  float mx[4], sm[4];
#pragma unroll
  for (int j = 0; j < 4; ++j)
    mx[j] = fmaxf(fmaxf(s[0][j], s[1][j]), fmaxf(s[2][j], s[3][j]));
#pragma unroll
  for (int xm = 1; xm <= 8; xm <<= 1)
#pragma unroll
    for (int j = 0; j < 4; ++j) mx[j] = fmaxf(mx[j], __shfl_xor(mx[j], xm));
#pragma unroll
  for (int j = 0; j < 4; ++j) sm[j] = 0.f;
#pragma unroll
  for (int n = 0; n < 4; ++n)
#pragma unroll
    for (int j = 0; j < 4; ++j) {
      const float e = __expf(s[n][j] - mx[j]);
      s[n][j] = e;
      sm[j] += e;
    }
#pragma unroll
  for (int xm = 1; xm <= 8; xm <<= 1)
#pragma unroll
    for (int j = 0; j < 4; ++j) sm[j] += __shfl_xor(sm[j], xm);
#pragma unroll
  for (int j = 0; j < 4; ++j) sm[j] = 1.f / sm[j];
#pragma unroll
  for (int n = 0; n < 4; ++n)
#pragma unroll
    for (int j = 0; j < 4; ++j)
      lp[(row0 + j) * 72 + n * 16 + lr] = f2bf(s[n][j] * sm[j]);
  __syncthreads();

  // O = P @ V
  f32x4 o[2];
  o[0] = (f32x4){0.f, 0.f, 0.f, 0.f};
  o[1] = o[0];
#pragma unroll
  for (int kk = 0; kk < 2; ++kk) {
    bf16x8 pa = *(const bf16x8*)(lp + (wid * 16 + lr) * 72 + kk * 32 + lk8);
#pragma unroll
    for (int d = 0; d < 2; ++d) {
      bf16x8 vb = *(const bf16x8*)(lvT + (d * 16 + lr) * 72 + kk * 32 + lk8);
      o[d] = __builtin_amdgcn_mfma_f32_16x16x32_bf16(pa, vb, o[d], 0, 0, 0);
    }
  }
#pragma unroll
  for (int d = 0; d < 2; ++d) {
    const int col = h * 32 + d * 16 + lr;
#pragma unroll
    for (int j = 0; j < 4; ++j) {
      const int row = row0 + j;
      out[(size_t)(b * 64 + row) * 512 + col] = f2bf(o[d][j]);
    }
  }
}

// ---------------- launch ----------------
extern "C" void kernel_launch(void* const* d_in, const int* in_sizes, int n_in,
                              void* d_out, int out_size, void* d_ws,
                              size_t ws_size, hipStream_t stream) {
  (void)in_sizes; (void)n_in; (void)out_size; (void)ws_size;
  const float* x = (const float*)d_in[0];
  const float* abias = (const float*)d_in[1];
  const float* mask = (const float*)d_in[2];
  const float* qkv_w = (const float*)d_in[3];
  const float* qkv_b = (const float*)d_in[4];
  const float* proj_w = (const float*)d_in[5];
  const float* proj_b = (const float*)d_in[6];

  char* ws = (char*)d_ws;
  unsigned short* ws_x = (unsigned short*)(ws);
  unsigned short* ws_qkv = (unsigned short*)(ws + 33554432);
  unsigned short* ws_wq = (unsigned short*)(ws + 134217728);
  unsigned short* ws_wp = (unsigned short*)(ws + 135790592);
  unsigned short* ws_att = ws_x;  // alias: x consumed by qkv GEMM before attn writes

  // one fused convert dispatch: x (16.7M) + qkv_w (786k) + proj_w (262k)
  convert_all_kernel<<<17408, 256, 0, stream>>>(x, qkv_w, proj_w, ws_x, ws_wq,
                                                ws_wp);

  // qkv: M=32768 (256 M-tiles), N=1536 (NT=12) -> 3072 blocks
  gemm128_kernel<true><<<3072, 512, 0, stream>>>(ws_x, ws_wq, qkv_b, ws_qkv,
                                                 32768, 1536, 512, 12);

  attn_kernel<<<8192, 256, 0, stream>>>(ws_qkv, abias, mask, ws_att);

  // proj: N=512 (NT=4) -> 1024 blocks
  gemm128_kernel<false><<<1024, 512, 0, stream>>>(ws_att, ws_wp, proj_b, d_out,
                                                  32768, 512, 512, 4);
}